// Round 1
// baseline (477.051 us; speedup 1.0000x reference)
//
#include <hip/hip_runtime.h>
#include <stdint.h>

// Shapes: B=16 T=8 C=2048 H=16 W=8 -> C8=256 C4=512 HW=128 NP=4
// NIMG = B*T = 128, M = NIMG*HW = 16384, Ncat = 2*C8 = 512, K = 2048

typedef _Float16 f16;
typedef _Float16 f16x8 __attribute__((ext_vector_type(8)));
typedef float f32x4 __attribute__((ext_vector_type(4)));

typedef const void __attribute__((address_space(1)))* gptr1;
typedef void __attribute__((address_space(3)))* lptr3;

__device__ __forceinline__ void gload16(const void* g, void* l) {
  __builtin_amdgcn_global_load_lds((gptr1)g, (lptr3)l, 16, 0, 0);
}

__device__ __forceinline__ float sigmoidf_(float x) { return 1.f / (1.f + expf(-x)); }

// ---------------- P1: transpose re_featmap (n,k,hw) -> At[m=n*128+hw][k] fp16 hi/lo,
// chunk-XOR pre-swizzled within each 64-k block (chunk c stored at c ^ (m&7)) ----
__global__ __launch_bounds__(256) void kP1(const float* __restrict__ x,
                                           f16* __restrict__ Ahi, f16* __restrict__ Alo) {
  int n = blockIdx.x >> 5;
  int k0 = (blockIdx.x & 31) * 64;
  __shared__ float L[64][129];
  int t = threadIdx.x;
  const float* src = x + (size_t)n * 262144 + (size_t)k0 * 128;
  for (int r = 0; r < 8; ++r) {
    int f = r * 256 + t;             // 2048 float4
    int kk = f >> 5, c4 = (f & 31) * 4;
    float4 v = *(const float4*)(src + kk * 128 + c4);
    L[kk][c4 + 0] = v.x; L[kk][c4 + 1] = v.y; L[kk][c4 + 2] = v.z; L[kk][c4 + 3] = v.w;
  }
  __syncthreads();
  for (int r = 0; r < 4; ++r) {
    int id = r * 256 + t;            // 1024 = 128 hw * 8 chunks
    int hw = id >> 3, c = id & 7;
    int cs = c ^ (hw & 7);           // source (logical) chunk for dest chunk c
    f16x8 h8, l8;
    for (int j = 0; j < 8; ++j) {
      float v = L[cs * 8 + j][hw];
      f16 h = (f16)v;
      h8[j] = h;
      l8[j] = (f16)(v - (float)h);
    }
    size_t m = (size_t)n * 128 + hw;
    size_t ob = m * 2048 + (size_t)k0 + (size_t)c * 8;
    *(f16x8*)(Ahi + ob) = h8;
    *(f16x8*)(Alo + ob) = l8;
  }
}

// ---------------- P_W: Wcat[512][2048] = [gamma_w*gamma_s ; beta_w*beta_s] fp16 hi/lo, pre-swizzled
__global__ __launch_bounds__(256) void kPW(const float* __restrict__ gw, const float* __restrict__ gs,
                                           const float* __restrict__ bw, const float* __restrict__ bs,
                                           f16* __restrict__ Whi, f16* __restrict__ Wlo) {
  int id = blockIdx.x * 256 + threadIdx.x;  // 131072 = 512 o * 256 chunks
  int o = id >> 8, cch = id & 255;
  float s; const float* row;
  if (o < 256) { s = gs[o]; row = gw + (size_t)o * 2048; }
  else         { s = bs[o - 256]; row = bw + (size_t)(o - 256) * 2048; }
  int kb = cch >> 3, sub = cch & 7;
  int subd = sub ^ (o & 7);
  f16x8 h8, l8;
  for (int j = 0; j < 8; ++j) {
    float v = row[cch * 8 + j] * s;
    f16 h = (f16)v;
    h8[j] = h;
    l8[j] = (f16)(v - (float)h);
  }
  size_t ob = (size_t)o * 2048 + (size_t)kb * 64 + (size_t)subd * 8;
  *(f16x8*)(Whi + ob) = h8;
  *(f16x8*)(Wlo + ob) = l8;
}

// ---------------- P_small: transposed small weights (scale folded) + vect transpose ----
__global__ __launch_bounds__(256) void kPS(const float* __restrict__ gg_w, const float* __restrict__ gg_s,
                                           const float* __restrict__ tte_w, const float* __restrict__ tte_s,
                                           const float* __restrict__ vect,
                                           float* __restrict__ ggT, float* __restrict__ tteT,
                                           float* __restrict__ vectT) {
  int id = blockIdx.x * 256 + threadIdx.x;
  if (id < 32768) {
    int c = id >> 7, o = id & 127;
    ggT[c * 128 + o] = gg_s[o] * gg_w[o * 256 + c];
  } else if (id < 65536) {
    int i = id - 32768; int c = i >> 7, o = i & 127;
    tteT[c * 128 + o] = tte_s[o] * tte_w[o * 256 + c];
  } else {
    int i = id - 65536;  // 262144 = 2048 c * 128 bt
    int c = i >> 7, bt = i & 127;
    vectT[c * 128 + bt] = vect[(size_t)bt * 2048 + c];
  }
}

// ---------------- Stage A GEMM: C[16384][512] = At * Wcat^T, fp16 3-term split MFMA ----
// BM=128 BN=128 BK=64; grid (128,4); 4 waves 2x2, each 64x64 via 4x4 16x16x32 frags.
__global__ __launch_bounds__(256, 2) void kGemmA(const f16* __restrict__ Ahi, const f16* __restrict__ Alo,
                                                 const f16* __restrict__ Whi, const f16* __restrict__ Wlo,
                                                 const float* __restrict__ gamma_b, const float* __restrict__ beta_b,
                                                 float* __restrict__ gammaF, float* __restrict__ betaF) {
  __shared__ __align__(16) f16 sAh[128 * 64];
  __shared__ __align__(16) f16 sAl[128 * 64];
  __shared__ __align__(16) f16 sWh[128 * 64];
  __shared__ __align__(16) f16 sWl[128 * 64];
  int t = threadIdx.x;
  int lane = t & 63, wid = t >> 6;
  int wr = wid >> 1, wc = wid & 1;
  int M0 = blockIdx.x * 128;
  int N0 = blockIdx.y * 128;
  int rl = lane >> 3;   // row within 8-row group
  int cl = lane & 7;    // 16B chunk
  f32x4 acc[4][4] = {};
  for (int kt = 0; kt < 32; ++kt) {
    int k0 = kt * 64;
    for (int i = 0; i < 4; ++i) {
      int rg = wid * 4 + i;            // region 0..15 (8 rows each)
      int r = rg * 8 + rl;
      size_t ga = ((size_t)(M0 + r) * 2048 + (size_t)k0) * 2 + (size_t)cl * 16;
      size_t gw = ((size_t)(N0 + r) * 2048 + (size_t)k0) * 2 + (size_t)cl * 16;
      gload16((const char*)Ahi + ga, (char*)sAh + rg * 1024);
      gload16((const char*)Alo + ga, (char*)sAl + rg * 1024);
      gload16((const char*)Whi + gw, (char*)sWh + rg * 1024);
      gload16((const char*)Wlo + gw, (char*)sWl + rg * 1024);
    }
    __syncthreads();   // compiler emits vmcnt(0) drain before s_barrier
    for (int ks = 0; ks < 2; ++ks) {
      int cg = ks * 4 + (lane >> 4);
      f16x8 ah[4], al[4], bh[4], bl[4];
      for (int mi = 0; mi < 4; ++mi) {
        int m = wr * 64 + mi * 16 + (lane & 15);
        int off = m * 64 + ((cg ^ (m & 7)) << 3);
        ah[mi] = *(const f16x8*)(sAh + off);
        al[mi] = *(const f16x8*)(sAl + off);
      }
      for (int ni = 0; ni < 4; ++ni) {
        int nn = wc * 64 + ni * 16 + (lane & 15);
        int off = nn * 64 + ((cg ^ (nn & 7)) << 3);
        bh[ni] = *(const f16x8*)(sWh + off);
        bl[ni] = *(const f16x8*)(sWl + off);
      }
      for (int mi = 0; mi < 4; ++mi)
        for (int ni = 0; ni < 4; ++ni) {
          acc[mi][ni] = __builtin_amdgcn_mfma_f32_16x16x32_f16(ah[mi], bh[ni], acc[mi][ni], 0, 0, 0);
          acc[mi][ni] = __builtin_amdgcn_mfma_f32_16x16x32_f16(ah[mi], bl[ni], acc[mi][ni], 0, 0, 0);
          acc[mi][ni] = __builtin_amdgcn_mfma_f32_16x16x32_f16(al[mi], bh[ni], acc[mi][ni], 0, 0, 0);
        }
    }
    __syncthreads();
  }
  // epilogue: +bias, relu, store fp32 to gammaF/betaF[n][o][hw]
  bool isBeta = (blockIdx.y >= 2);
  const float* bias = isBeta ? beta_b : gamma_b;
  float* outb = isBeta ? betaF : gammaF;
  int nimg = blockIdx.x;
  for (int mi = 0; mi < 4; ++mi) {
    int hwb = wr * 64 + mi * 16 + ((lane >> 4) << 2);   // C/D: row=(lane>>4)*4+reg (M dim = hw)
    for (int ni = 0; ni < 4; ++ni) {
      int og = N0 + wc * 64 + ni * 16 + (lane & 15);    // C/D: col=lane&15 (N dim = channel)
      int o = og & 255;
      float bb = bias[o];
      f32x4 v = acc[mi][ni];
      float4 w;
      w.x = fmaxf(v[0] + bb, 0.f);
      w.y = fmaxf(v[1] + bb, 0.f);
      w.z = fmaxf(v[2] + bb, 0.f);
      w.w = fmaxf(v[3] + bb, 0.f);
      *(float4*)(outb + (size_t)nimg * 32768 + (size_t)o * 128 + hwb) = w;
    }
  }
}

// ---------------- Gs: per (b,p): Gs0 = g0^T b1, Gs1 = g1^T b0 (fp32, K=256) ----
__global__ __launch_bounds__(256, 2) void kGs(const float* __restrict__ gammaF, const float* __restrict__ betaF,
                                              float* __restrict__ Gs0, float* __restrict__ Gs1) {
  int n = blockIdx.x;      // bp = b*4+p
  int which = blockIdx.y;  // 0 -> Gs0, 1 -> Gs1
  int b = n >> 2, p = n & 3;
  int tg = 2 * p + which;
  int tb = 2 * p + 1 - which;
  const float* A = gammaF + (size_t)(b * 8 + tg) * 32768;   // [c][s]
  const float* Bm = betaF + (size_t)(b * 8 + tb) * 32768;   // [c][t]
  float* out = (which ? Gs1 : Gs0) + (size_t)n * 16384;
  __shared__ __align__(16) float As[16 * 128];
  __shared__ __align__(16) float Bs[16 * 128];
  int t = threadIdx.x;
  int ty = t >> 4, tx = t & 15;
  float acc[8][8] = {};
  for (int c0 = 0; c0 < 256; c0 += 16) {
    for (int r = 0; r < 2; ++r) {
      int f = r * 256 + t;            // 512 float4
      int cc = f >> 5, col = (f & 31) * 4;
      *(float4*)(As + cc * 128 + col) = *(const float4*)(A + (size_t)(c0 + cc) * 128 + col);
      *(float4*)(Bs + cc * 128 + col) = *(const float4*)(Bm + (size_t)(c0 + cc) * 128 + col);
    }
    __syncthreads();
    for (int cc = 0; cc < 16; ++cc) {
      float a8[8], b8[8];
      *(float4*)a8 = *(const float4*)(As + cc * 128 + ty * 8);
      *(float4*)(a8 + 4) = *(const float4*)(As + cc * 128 + ty * 8 + 4);
      *(float4*)b8 = *(const float4*)(Bs + cc * 128 + tx * 8);
      *(float4*)(b8 + 4) = *(const float4*)(Bs + cc * 128 + tx * 8 + 4);
      for (int i = 0; i < 8; ++i)
        for (int j = 0; j < 8; ++j)
          acc[i][j] = fmaf(a8[i], b8[j], acc[i][j]);
    }
    __syncthreads();
  }
  for (int i = 0; i < 8; ++i) {
    *(float4*)(out + (size_t)(ty * 8 + i) * 128 + tx * 8) =
        make_float4(acc[i][0], acc[i][1], acc[i][2], acc[i][3]);
    *(float4*)(out + (size_t)(ty * 8 + i) * 128 + tx * 8 + 4) =
        make_float4(acc[i][4], acc[i][5], acc[i][6], acc[i][7]);
  }
}

// ---------------- theta: thetaO[b][o][t] = relu(theta_w . vect + theta_b) ----
__global__ __launch_bounds__(256) void kTheta(const float* __restrict__ vectT, const float* __restrict__ thw,
                                              const float* __restrict__ thb, float* __restrict__ thetaO) {
  int oq = blockIdx.x;  // 64 blocks * 4 o
  int t = threadIdx.x;
  int bt = t & 127, half = t >> 7;
  float acc[4] = {0.f, 0.f, 0.f, 0.f};
  const float* v = vectT + (size_t)half * 1024 * 128;
  for (int c = 0; c < 1024; ++c) {
    float x = v[(size_t)c * 128 + bt];
    for (int j = 0; j < 4; ++j)
      acc[j] = fmaf(thw[(size_t)(oq * 4 + j) * 2048 + half * 1024 + c], x, acc[j]);
  }
  __shared__ float R[256][4];
  for (int j = 0; j < 4; ++j) R[t][j] = acc[j];
  __syncthreads();
  if (t < 128) {
    int b = t >> 3, tt = t & 7;
    for (int j = 0; j < 4; ++j) {
      int o = oq * 4 + j;
      float val = fmaxf(R[t][j] + R[t + 128][j] + thb[o], 0.f);
      thetaO[(size_t)b * 2048 + o * 8 + tt] = val;
    }
  }
}

// ---------------- MLP: p00/p01 = sigmoid(W2 relu(W1 [c0,c1] + b1) + b2) ----
__global__ __launch_bounds__(256) void kMlp(const float* __restrict__ thetaO,
                                            const float* __restrict__ w1, const float* __restrict__ b1,
                                            const float* __restrict__ w2, const float* __restrict__ b2,
                                            float* __restrict__ p00, float* __restrict__ p01) {
  int bp = blockIdx.x;
  int b = bp >> 2, p = bp & 3;
  __shared__ float x0[256], x1[256], h1a[256], h1b[256];
  int t = threadIdx.x;
  x0[t] = thetaO[(size_t)b * 2048 + t * 8 + 2 * p];
  x1[t] = thetaO[(size_t)b * 2048 + t * 8 + 2 * p + 1];
  __syncthreads();
  {
    float aa = 0.f, ab = 0.f;
    const float* wr = w1 + (size_t)t * 512;
    for (int c = 0; c < 256; c += 4) {
      float4 w4 = *(const float4*)(wr + c);
      aa += w4.x * x0[c] + w4.y * x0[c + 1] + w4.z * x0[c + 2] + w4.w * x0[c + 3];
      ab += w4.x * x1[c] + w4.y * x1[c + 1] + w4.z * x1[c + 2] + w4.w * x1[c + 3];
    }
    for (int c = 0; c < 256; c += 4) {
      float4 w4 = *(const float4*)(wr + 256 + c);
      aa += w4.x * x1[c] + w4.y * x1[c + 1] + w4.z * x1[c + 2] + w4.w * x1[c + 3];
      ab += w4.x * x0[c] + w4.y * x0[c + 1] + w4.z * x0[c + 2] + w4.w * x0[c + 3];
    }
    h1a[t] = fmaxf(aa + b1[t], 0.f);
    h1b[t] = fmaxf(ab + b1[t], 0.f);
  }
  __syncthreads();
  for (int r = 0; r < 8; ++r) {
    int ch = r * 256 + t;
    const float* wr2 = w2 + (size_t)ch * 256;
    float sa = 0.f, sb = 0.f;
    for (int k = 0; k < 256; k += 4) {
      float4 w4 = *(const float4*)(wr2 + k);
      sa += w4.x * h1a[k] + w4.y * h1a[k + 1] + w4.z * h1a[k + 2] + w4.w * h1a[k + 3];
      sb += w4.x * h1b[k] + w4.y * h1b[k + 1] + w4.z * h1b[k + 2] + w4.w * h1b[k + 3];
    }
    p00[(size_t)bp * 2048 + ch] = sigmoidf_(sa + b2[ch]);
    p01[(size_t)bp * 2048 + ch] = sigmoidf_(sb + b2[ch]);
  }
}

// ---------------- ta-part of gate: Sta[gate][n][hw] = sum_o te_w[o]*relu(tteT . ecat + tte_b) ----
__global__ __launch_bounds__(256, 2) void kTa(const float* __restrict__ embed, const float* __restrict__ tteT,
                                              const float* __restrict__ tte_b, const float* __restrict__ te_w,
                                              float* __restrict__ Sta) {
  int n = blockIdx.x, gate = blockIdx.y;
  int b = n >> 2, p = n & 3;
  __shared__ __align__(16) float E[256 * 128];
  __shared__ float Red[16 * 128];
  int t = threadIdx.x;
  const float* eA = embed + (size_t)(b * 8 + 2 * p + gate) * 16384;
  const float* eB = embed + (size_t)(b * 8 + 2 * p + 1 - gate) * 16384;
  for (int r = 0; r < 16; ++r) {
    int f = r * 256 + t;
    int ch = f >> 5, c4 = (f & 31) * 4;
    *(float4*)(E + ch * 128 + c4) = *(const float4*)(eA + (size_t)ch * 128 + c4);
  }
  for (int r = 0; r < 16; ++r) {
    int f = r * 256 + t;
    int ch = f >> 5, c4 = (f & 31) * 4;
    *(float4*)(E + (128 + ch) * 128 + c4) = *(const float4*)(eB + (size_t)ch * 128 + c4);
  }
  __syncthreads();
  int ty = t >> 4, tx = t & 15;
  float acc[8][8] = {};
  for (int c = 0; c < 256; ++c) {
    float w8[8], g8[8];
    *(float4*)w8 = *(const float4*)(tteT + (size_t)c * 128 + ty * 8);
    *(float4*)(w8 + 4) = *(const float4*)(tteT + (size_t)c * 128 + ty * 8 + 4);
    *(float4*)g8 = *(const float4*)(E + c * 128 + tx * 8);
    *(float4*)(g8 + 4) = *(const float4*)(E + c * 128 + tx * 8 + 4);
    for (int i = 0; i < 8; ++i)
      for (int j = 0; j < 8; ++j)
        acc[i][j] = fmaf(w8[i], g8[j], acc[i][j]);
  }
  float par[8];
  for (int j = 0; j < 8; ++j) par[j] = 0.f;
  for (int i = 0; i < 8; ++i) {
    int o = ty * 8 + i;
    float tb = tte_b[o], tw = te_w[o];
    for (int j = 0; j < 8; ++j)
      par[j] += tw * fmaxf(acc[i][j] + tb, 0.f);
  }
  for (int j = 0; j < 8; ++j) Red[ty * 128 + tx * 8 + j] = par[j];
  __syncthreads();
  if (t < 128) {
    float s = 0.f;
    for (int g = 0; g < 16; ++g) s += Red[g * 128 + t];
    Sta[(size_t)gate * 8192 + n * 128 + t] = s;
  }
}

// ---------------- gj-part of gate: Sgj[gate][n][hw] = sum_o te_w[128+o]*relu(ggT . j + gg_b) ----
__global__ __launch_bounds__(256, 2) void kGj(const float* __restrict__ Gs0, const float* __restrict__ Gs1,
                                              const float* __restrict__ ggT, const float* __restrict__ gg_b,
                                              const float* __restrict__ te_w, float* __restrict__ Sgj) {
  int n = blockIdx.x, gate = blockIdx.y;
  __shared__ float J[256 * 129];
  __shared__ float Red[16 * 128];
  int t = threadIdx.x;
  const float* srcT = (gate == 0 ? Gs0 : Gs1) + (size_t)n * 16384;  // rows 0..127 = transpose
  const float* srcC = (gate == 0 ? Gs1 : Gs0) + (size_t)n * 16384;  // rows 128..255 = copy
  for (int r = 0; r < 16; ++r) {
    int f = r * 256 + t;
    int hw = f >> 5, c4 = (f & 31) * 4;
    float4 v = *(const float4*)(srcT + (size_t)hw * 128 + c4);
    J[(c4 + 0) * 129 + hw] = v.x;
    J[(c4 + 1) * 129 + hw] = v.y;
    J[(c4 + 2) * 129 + hw] = v.z;
    J[(c4 + 3) * 129 + hw] = v.w;
  }
  for (int r = 0; r < 16; ++r) {
    int f = r * 256 + t;
    int c = f >> 5, h4 = (f & 31) * 4;
    float4 v = *(const float4*)(srcC + (size_t)c * 128 + h4);
    J[(128 + c) * 129 + h4 + 0] = v.x;
    J[(128 + c) * 129 + h4 + 1] = v.y;
    J[(128 + c) * 129 + h4 + 2] = v.z;
    J[(128 + c) * 129 + h4 + 3] = v.w;
  }
  __syncthreads();
  int ty = t >> 4, tx = t & 15;
  float acc[8][8] = {};
  for (int c = 0; c < 256; ++c) {
    float w8[8], g8[8];
    *(float4*)w8 = *(const float4*)(ggT + (size_t)c * 128 + ty * 8);
    *(float4*)(w8 + 4) = *(const float4*)(ggT + (size_t)c * 128 + ty * 8 + 4);
    for (int j = 0; j < 8; ++j) g8[j] = J[c * 129 + tx * 8 + j];
    for (int i = 0; i < 8; ++i)
      for (int j = 0; j < 8; ++j)
        acc[i][j] = fmaf(w8[i], g8[j], acc[i][j]);
  }
  float par[8];
  for (int j = 0; j < 8; ++j) par[j] = 0.f;
  for (int i = 0; i < 8; ++i) {
    int o = ty * 8 + i;
    float gb = gg_b[o], tw = te_w[128 + o];
    for (int j = 0; j < 8; ++j)
      par[j] += tw * fmaxf(acc[i][j] + gb, 0.f);
  }
  for (int j = 0; j < 8; ++j) Red[ty * 128 + tx * 8 + j] = par[j];
  __syncthreads();
  if (t < 128) {
    float s = 0.f;
    for (int g = 0; g < 16; ++g) s += Red[g * 128 + t];
    Sgj[(size_t)gate * 8192 + n * 128 + t] = s;
  }
}

// ---------------- gate sigmoid ----
__global__ __launch_bounds__(256) void kGate(const float* __restrict__ Sta, const float* __restrict__ Sgj,
                                             const float* __restrict__ te_s, const float* __restrict__ te_b,
                                             float* __restrict__ paArr) {
  int id = blockIdx.x * 256 + threadIdx.x;  // 16384
  float y = te_s[0] * (Sta[id] + Sgj[id]) + te_b[0];
  paArr[id] = sigmoidf_(y);
}

// ---------------- final elementwise: out = relu(p00*pa*f0 + p01*pb*f1)^2 ----
__global__ __launch_bounds__(256) void kFinal(const float* __restrict__ featmap, const float* __restrict__ p00,
                                              const float* __restrict__ p01, const float* __restrict__ paArr,
                                              float* __restrict__ out) {
  int fid = blockIdx.x * 256 + threadIdx.x;  // 4,194,304 float4 tasks
  int h4 = (fid & 31) * 4;
  int c = (fid >> 5) & 2047;
  int bp = fid >> 16;
  int b = bp >> 2, p = bp & 3;
  float ga = p00[(size_t)bp * 2048 + c];
  float gb = p01[(size_t)bp * 2048 + c];
  float4 pa4 = *(const float4*)(paArr + (size_t)bp * 128 + h4);
  float4 pb4 = *(const float4*)(paArr + 8192 + (size_t)bp * 128 + h4);
  const float* f0 = featmap + (size_t)(b * 8 + 2 * p) * 262144 + (size_t)c * 128 + h4;
  const float* f1 = f0 + 262144;
  float4 v0 = *(const float4*)f0;
  float4 v1 = *(const float4*)f1;
  float4 o4;
  float r;
  r = fmaxf(ga * pa4.x * v0.x + gb * pb4.x * v1.x, 0.f); o4.x = r * r;
  r = fmaxf(ga * pa4.y * v0.y + gb * pb4.y * v1.y, 0.f); o4.y = r * r;
  r = fmaxf(ga * pa4.z * v0.z + gb * pb4.z * v1.z, 0.f); o4.z = r * r;
  r = fmaxf(ga * pa4.w * v0.w + gb * pb4.w * v1.w, 0.f); o4.w = r * r;
  *(float4*)(out + (size_t)fid * 4) = o4;
}

extern "C" void kernel_launch(void* const* d_in, const int* in_sizes, int n_in,
                              void* d_out, int out_size, void* d_ws, size_t ws_size,
                              hipStream_t stream) {
  (void)in_sizes; (void)n_in; (void)out_size; (void)ws_size;
  const float* featmap    = (const float*)d_in[0];
  const float* re_featmap = (const float*)d_in[1];
  const float* vect       = (const float*)d_in[2];
  const float* embed      = (const float*)d_in[3];
  const float* gamma_w    = (const float*)d_in[4];
  const float* gamma_s    = (const float*)d_in[5];
  const float* gamma_b    = (const float*)d_in[6];
  const float* beta_w     = (const float*)d_in[7];
  const float* beta_s     = (const float*)d_in[8];
  const float* beta_b     = (const float*)d_in[9];
  const float* gg_w       = (const float*)d_in[10];
  const float* gg_s       = (const float*)d_in[11];
  const float* gg_b       = (const float*)d_in[12];
  const float* tte_w      = (const float*)d_in[13];
  const float* tte_s      = (const float*)d_in[14];
  const float* tte_b      = (const float*)d_in[15];
  const float* te_w       = (const float*)d_in[16];
  const float* te_s       = (const float*)d_in[17];
  const float* te_b       = (const float*)d_in[18];
  const float* theta_w    = (const float*)d_in[19];
  const float* theta_b    = (const float*)d_in[20];
  const float* cp_w1      = (const float*)d_in[21];
  const float* cp_b1      = (const float*)d_in[22];
  const float* cp_w2      = (const float*)d_in[23];
  const float* cp_b2      = (const float*)d_in[24];
  float* out = (float*)d_out;

  char* w = (char*)d_ws;
  f16* Ahi = (f16*)w;   w += (size_t)16384 * 2048 * 2;
  f16* Alo = (f16*)w;   w += (size_t)16384 * 2048 * 2;
  f16* Whi = (f16*)w;   w += (size_t)512 * 2048 * 2;
  f16* Wlo = (f16*)w;   w += (size_t)512 * 2048 * 2;
  float* gammaF = (float*)w; w += (size_t)128 * 256 * 128 * 4;
  float* betaF  = (float*)w; w += (size_t)128 * 256 * 128 * 4;
  float* Gs0    = (float*)w; w += (size_t)64 * 128 * 128 * 4;
  float* Gs1    = (float*)w; w += (size_t)64 * 128 * 128 * 4;
  float* ggT    = (float*)w; w += (size_t)256 * 128 * 4;
  float* tteT   = (float*)w; w += (size_t)256 * 128 * 4;
  float* vectT  = (float*)w; w += (size_t)2048 * 128 * 4;
  float* thetaO = (float*)w; w += (size_t)16 * 256 * 8 * 4;
  float* Sta    = (float*)w; w += (size_t)2 * 64 * 128 * 4;
  float* Sgj    = (float*)w; w += (size_t)2 * 64 * 128 * 4;
  float* paArr  = (float*)w; w += (size_t)2 * 64 * 128 * 4;
  float* p00    = (float*)w; w += (size_t)64 * 2048 * 4;
  float* p01    = (float*)w; w += (size_t)64 * 2048 * 4;

  kP1<<<4096, 256, 0, stream>>>(re_featmap, Ahi, Alo);
  kPW<<<512, 256, 0, stream>>>(gamma_w, gamma_s, beta_w, beta_s, Whi, Wlo);
  kPS<<<1280, 256, 0, stream>>>(gg_w, gg_s, tte_w, tte_s, vect, ggT, tteT, vectT);
  kGemmA<<<dim3(128, 4), 256, 0, stream>>>(Ahi, Alo, Whi, Wlo, gamma_b, beta_b, gammaF, betaF);
  kGs<<<dim3(64, 2), 256, 0, stream>>>(gammaF, betaF, Gs0, Gs1);
  kTheta<<<64, 256, 0, stream>>>(vectT, theta_w, theta_b, thetaO);
  kMlp<<<64, 256, 0, stream>>>(thetaO, cp_w1, cp_b1, cp_w2, cp_b2, p00, p01);
  kTa<<<dim3(64, 2), 256, 0, stream>>>(embed, tteT, tte_b, te_w, Sta);
  kGj<<<dim3(64, 2), 256, 0, stream>>>(Gs0, Gs1, ggT, gg_b, te_w, Sgj);
  kGate<<<64, 256, 0, stream>>>(Sta, Sgj, te_s, te_b, paArr);
  kFinal<<<16384, 256, 0, stream>>>(featmap, p00, p01, paArr, out);
}